// Round 5
// baseline (172.985 us; speedup 1.0000x reference)
//
#include <hip/hip_runtime.h>

#define TT 1024
#define BB 4096
#define CHUNK 64
#define WARM 320
#define NCH (TT / CHUNK)          // 16 chunks
#define NSTEPMAX (WARM + CHUNK)   // 384

// quad_perm DPP broadcast within 4-lane groups
template<int CTRL>
__device__ __forceinline__ float qperm(float v) {
    int i = __builtin_bit_cast(int, v);
    i = __builtin_amdgcn_mov_dpp(i, CTRL, 0xF, 0xF, true);
    return __builtin_bit_cast(float, i);
}

// One wave per block; 4 independent chains (ILP) x 16 elements = 64 elements.
// Lane j=lane&3 owns hidden unit j of element n*16+(lane>>2) for chain n.
// State r = 1/(exp2(z')+1), params p = 1-r. Chunked time axis, WARM warmup.
__launch_bounds__(64, 1)
__global__ void bkt_rnn_k(const float* __restrict__ x,
                          const float* __restrict__ y,
                          const float* __restrict__ prior,
                          const float* __restrict__ W_ih,
                          const float* __restrict__ W_hh,
                          const float* __restrict__ b_ih,
                          const float* __restrict__ b_hh,
                          float* __restrict__ out,
                          float* __restrict__ lossPart)
{
    __shared__ unsigned char xls[NSTEPMAX * 64];  // x bits, [row][col]
    __shared__ unsigned char yls[CHUNK * 64];     // y bits, [row][col]
    __shared__ float cbuf[16 * 64];               // flush: corr
    __shared__ float nbuf[16 * 64];               // flush: next_latent

    const int lane = threadIdx.x;
    const int j  = lane & 3;
    const int le = lane >> 2;              // element-within-chain 0..15
    const int c  = blockIdx.x >> 6;        // chunk 0..15
    const int eg = blockIdx.x & 63;        // element group
    const int e0 = eg * 64;

    const int t_out0  = c * CHUNK;
    const int nwarm   = (t_out0 > WARM) ? WARM : t_out0;
    const int t_start = t_out0 - nwarm;
    const int nsteps  = nwarm + CHUNK;     // multiple of 4

    const int cc4 = (lane & 15) * 4;       // staging/flush column
    const int rof = lane >> 4;             // staging/flush row offset 0..3

    // ---- stage x (window) and y (output range) as 0/1 bytes, coalesced float4
    for (int rb = 0; rb < nsteps; rb += 4) {
        const int r = rb + rof;
        float4 v = *(const float4*)&x[(size_t)(t_start + r) * BB + e0 + cc4];
        unsigned w = (v.x != 0.f ? 1u : 0u) | (v.y != 0.f ? 0x100u : 0u)
                   | (v.z != 0.f ? 0x10000u : 0u) | (v.w != 0.f ? 0x1000000u : 0u);
        *(unsigned*)&xls[r * 64 + cc4] = w;
    }
    for (int rb = 0; rb < CHUNK; rb += 4) {
        const int r = rb + rof;
        float4 v = *(const float4*)&y[(size_t)(t_out0 + r) * BB + e0 + cc4];
        unsigned w = (v.x != 0.f ? 1u : 0u) | (v.y != 0.f ? 0x100u : 0u)
                   | (v.z != 0.f ? 0x10000u : 0u) | (v.w != 0.f ? 0x1000000u : 0u);
        *(unsigned*)&yls[r * 64 + cc4] = w;
    }
    __syncthreads();

    // ---- constants (r-form, 2*log2e folded)
    const float S = 2.8853900817779268f;
    const float wj0 = W_hh[j * 4 + (j ^ 0)];
    const float wj1 = W_hh[j * 4 + (j ^ 1)];
    const float wj2 = W_hh[j * 4 + (j ^ 2)];
    const float wj3 = W_hh[j * 4 + (j ^ 3)];
    const float v0 = -2.f * S * wj0, v1 = -2.f * S * wj1;
    const float v2 = -2.f * S * wj2, v3 = -2.f * S * wj3;
    const float base0 = S * (b_ih[j] + b_hh[j] + wj0 + wj1 + wj2 + wj3);
    const float base1 = base0 + S * W_ih[j];

    const float sig = 1.0f / (1.0f + __builtin_amdgcn_exp2f(-1.4426950408889634f * prior[0]));
    float rq0[4], rq1[4], rq2[4], rq3[4], lat[4];
    #pragma unroll
    for (int n = 0; n < 4; ++n) { rq0[n] = rq1[n] = rq2[n] = rq3[n] = 0.5f; lat[n] = sig; }

    // ---- warmup: 4 interleaved independent chains (trans latency hidden by ILP)
    #pragma unroll 4
    for (int s = 0; s < nwarm; ++s) {
        #pragma unroll
        for (int n = 0; n < 4; ++n) {
            float cxb = xls[s * 64 + n * 16 + le] ? base1 : base0;
            float t0 = fmaf(rq0[n], v0, cxb);
            float u  = rq3[n] * v3;
            float t1 = fmaf(rq1[n], v1, u);
            float t2 = fmaf(rq2[n], v2, t0);
            float z  = t1 + t2;
            float ex = __builtin_amdgcn_exp2f(z);
            float r  = __builtin_amdgcn_rcpf(ex + 1.0f);
            rq0[n] = r;
            rq1[n] = qperm<0xB1>(r);
            rq2[n] = qperm<0x4E>(r);
            rq3[n] = qperm<0x1B>(r);
            lat[n] = fmaf(lat[n], (rq0[n] + rq1[n]) - 1.0f, 1.0f - rq0[n]);
        }
    }

    // ---- output: 4 groups of 16 steps, LDS-buffered flush + fused BCE
    float lossAcc = 0.0f;
    for (int g = 0; g < 4; ++g) {
        #pragma unroll 4
        for (int i = 0; i < 16; ++i) {
            const int s = nwarm + g * 16 + i;
            #pragma unroll
            for (int n = 0; n < 4; ++n) {
                float cxb = xls[s * 64 + n * 16 + le] ? base1 : base0;
                float t0 = fmaf(rq0[n], v0, cxb);
                float u  = rq3[n] * v3;
                float t1 = fmaf(rq1[n], v1, u);
                float t2 = fmaf(rq2[n], v2, t0);
                float z  = t1 + t2;
                float ex = __builtin_amdgcn_exp2f(z);
                float r  = __builtin_amdgcn_rcpf(ex + 1.0f);
                rq0[n] = r;
                rq1[n] = qperm<0xB1>(r);
                rq2[n] = qperm<0x4E>(r);
                rq3[n] = qperm<0x1B>(r);
                float corr = fmaf(lat[n], (rq2[n] + rq3[n]) - 1.0f, 1.0f - rq2[n]);
                float nl   = fmaf(lat[n], (rq0[n] + rq1[n]) - 1.0f, 1.0f - rq0[n]);
                if (j == 0) {
                    cbuf[i * 64 + n * 16 + le] = corr;
                    nbuf[i * 64 + n * 16 + le] = nl;
                }
                lat[n] = nl;
            }
        }
        __syncthreads();
        const int tg = t_out0 + g * 16;
        #pragma unroll
        for (int k = 0; k < 4; ++k) {
            const int row = k * 4 + rof;
            float4 cv = *(const float4*)&cbuf[row * 64 + cc4];
            float4 nv = *(const float4*)&nbuf[row * 64 + cc4];
            float* cO = out + (size_t)(tg + row) * BB + e0 + cc4;
            *(float4*)cO = cv;
            *(float4*)(cO + (size_t)TT * BB) = nv;
            unsigned yw = *(const unsigned*)&yls[(g * 16 + row) * 64 + cc4];
            auto bce = [&](float cvv, unsigned bit) {
                float lp = bit ? cvv : (1.0f - cvv);
                lossAcc += fmaxf(__builtin_amdgcn_logf(lp) * 0.6931471805599453f, -100.0f);
            };
            bce(cv.x, yw & 0xFFu);     bce(cv.y, yw & 0xFF00u);
            bce(cv.z, yw & 0xFF0000u); bce(cv.w, yw & 0xFF000000u);
        }
        __syncthreads();
    }

    #pragma unroll
    for (int o = 32; o >= 1; o >>= 1) lossAcc += __shfl_xor(lossAcc, o, 64);
    if (lane == 0) lossPart[blockIdx.x] = lossAcc;
}

// Reduce 1024 per-block partials -> final mean NLL
__global__ void reduce_k(const float* __restrict__ part, float* __restrict__ loss) {
    float acc = 0.f;
    for (int i = threadIdx.x; i < 1024; i += 256) acc += part[i];
    #pragma unroll
    for (int o = 32; o >= 1; o >>= 1) acc += __shfl_xor(acc, o, 64);
    __shared__ float w[4];
    if ((threadIdx.x & 63) == 0) w[threadIdx.x >> 6] = acc;
    __syncthreads();
    if (threadIdx.x == 0) {
        float t = w[0] + w[1] + w[2] + w[3];
        *loss = t * (-1.0f / ((float)TT * (float)BB));
    }
}

extern "C" void kernel_launch(void* const* d_in, const int* in_sizes, int n_in,
                              void* d_out, int out_size, void* d_ws, size_t ws_size,
                              hipStream_t stream) {
    const float* x    = (const float*)d_in[0];
    const float* y    = (const float*)d_in[1];
    const float* pr   = (const float*)d_in[2];
    const float* W_ih = (const float*)d_in[3];
    const float* W_hh = (const float*)d_in[4];
    const float* b_ih = (const float*)d_in[5];
    const float* b_hh = (const float*)d_in[6];
    float* out = (float*)d_out;
    float* lossPart = (float*)d_ws;  // 1024 floats

    bkt_rnn_k<<<NCH * 64, 64, 0, stream>>>(x, y, pr, W_ih, W_hh, b_ih, b_hh, out, lossPart);
    reduce_k<<<1, 256, 0, stream>>>(lossPart, out + 2 * (size_t)TT * BB);
}

// Round 6
// 130.281 us; speedup vs baseline: 1.3278x; 1.3278x over previous
//
#include <hip/hip_runtime.h>

#define TT 1024
#define BB 4096
#define CHUNK 64
#define WARM 256
#define NCH (TT / CHUNK)            // 16 chunks
#define NSTEPMAX (WARM + CHUNK)     // 320

// One wave per block; one LANE per element (all 4 hidden units in-lane).
// No cross-lane ops, no DPP, coalesced direct stores (lane = consecutive e).
// State r_j = 1/(exp2(z'_j)+1); h_j = 1-2r_j; params p_j = 1-r_j.
__launch_bounds__(64, 1)
__global__ void bkt_rnn_k(const float* __restrict__ x,
                          const float* __restrict__ y,
                          const float* __restrict__ prior,
                          const float* __restrict__ W_ih,
                          const float* __restrict__ W_hh,
                          const float* __restrict__ b_ih,
                          const float* __restrict__ b_hh,
                          float* __restrict__ out,
                          float* __restrict__ lossPart)
{
    __shared__ unsigned char xls[NSTEPMAX * 64];  // x in {0,1} bytes, [row][lane]
    __shared__ unsigned char yls[CHUNK * 64];     // y bytes, [row][lane]

    const int lane = threadIdx.x;
    const int c  = blockIdx.x >> 6;        // chunk 0..15
    const int eg = blockIdx.x & 63;        // element group
    const int e0 = eg * 64;
    const int e  = e0 + lane;

    const int t_out0  = c * CHUNK;
    const int nwarm   = (t_out0 > WARM) ? WARM : t_out0;
    const int t_start = t_out0 - nwarm;
    const int nsteps  = nwarm + CHUNK;     // multiple of 4

    // ---- stage x window + y output range as 0/1 bytes (coalesced float4 reads)
    const int c4  = (lane & 15) * 4;
    const int rof = lane >> 4;
    for (int rb = 0; rb < nsteps; rb += 4) {
        const int r = rb + rof;
        float4 v = *(const float4*)&x[(size_t)(t_start + r) * BB + e0 + c4];
        unsigned w = (v.x != 0.f ? 1u : 0u) | (v.y != 0.f ? 0x100u : 0u)
                   | (v.z != 0.f ? 0x10000u : 0u) | (v.w != 0.f ? 0x1000000u : 0u);
        *(unsigned*)&xls[r * 64 + c4] = w;
    }
    for (int rb = 0; rb < CHUNK; rb += 4) {
        const int r = rb + rof;
        float4 v = *(const float4*)&y[(size_t)(t_out0 + r) * BB + e0 + c4];
        unsigned w = (v.x != 0.f ? 1u : 0u) | (v.y != 0.f ? 0x100u : 0u)
                   | (v.z != 0.f ? 0x10000u : 0u) | (v.w != 0.f ? 0x1000000u : 0u);
        *(unsigned*)&yls[r * 64 + c4] = w;
    }
    __syncthreads();

    // ---- constants (r-form, S = 2*log2(e) folded). All scalar (SGPR) values.
    const float S = 2.8853900817779268f;
    float base[4], sw[4], v_[4][4];
    #pragma unroll
    for (int jj = 0; jj < 4; ++jj) {
        float rowsum = W_hh[jj * 4 + 0] + W_hh[jj * 4 + 1] + W_hh[jj * 4 + 2] + W_hh[jj * 4 + 3];
        base[jj] = S * (b_ih[jj] + b_hh[jj] + rowsum);
        sw[jj]   = S * W_ih[jj];
        #pragma unroll
        for (int kk = 0; kk < 4; ++kk) v_[jj][kk] = -2.f * S * W_hh[jj * 4 + kk];
    }

    float lat = 1.0f / (1.0f + __builtin_amdgcn_exp2f(-1.4426950408889634f * prior[0]));
    float r0 = 0.5f, r1 = 0.5f, r2 = 0.5f, r3 = 0.5f;  // h = 0
    float lossAcc = 0.0f;

    float* cO = out + e;
    float* lO = out + (size_t)TT * BB + e;

    // ---- warmup (no outputs)
    #pragma unroll 4
    for (int s = 0; s < nwarm; ++s) {
        float xf = (float)xls[s * 64 + lane];
        float z0 = fmaf(xf, sw[0], base[0]);
        float z1 = fmaf(xf, sw[1], base[1]);
        float z2 = fmaf(xf, sw[2], base[2]);
        float z3 = fmaf(xf, sw[3], base[3]);
        z0 = fmaf(r0, v_[0][0], z0); z0 = fmaf(r1, v_[0][1], z0);
        z0 = fmaf(r2, v_[0][2], z0); z0 = fmaf(r3, v_[0][3], z0);
        z1 = fmaf(r0, v_[1][0], z1); z1 = fmaf(r1, v_[1][1], z1);
        z1 = fmaf(r2, v_[1][2], z1); z1 = fmaf(r3, v_[1][3], z1);
        z2 = fmaf(r0, v_[2][0], z2); z2 = fmaf(r1, v_[2][1], z2);
        z2 = fmaf(r2, v_[2][2], z2); z2 = fmaf(r3, v_[2][3], z2);
        z3 = fmaf(r0, v_[3][0], z3); z3 = fmaf(r1, v_[3][1], z3);
        z3 = fmaf(r2, v_[3][2], z3); z3 = fmaf(r3, v_[3][3], z3);
        r0 = __builtin_amdgcn_rcpf(__builtin_amdgcn_exp2f(z0) + 1.0f);
        r1 = __builtin_amdgcn_rcpf(__builtin_amdgcn_exp2f(z1) + 1.0f);
        r2 = __builtin_amdgcn_rcpf(__builtin_amdgcn_exp2f(z2) + 1.0f);
        r3 = __builtin_amdgcn_rcpf(__builtin_amdgcn_exp2f(z3) + 1.0f);
        lat = fmaf(lat, (r0 + r1) - 1.0f, 1.0f - r0);
    }

    // ---- output phase: direct coalesced stores + inline BCE
    #pragma unroll 4
    for (int i = 0; i < CHUNK; ++i) {
        const int s = nwarm + i;
        float xf = (float)xls[s * 64 + lane];
        float z0 = fmaf(xf, sw[0], base[0]);
        float z1 = fmaf(xf, sw[1], base[1]);
        float z2 = fmaf(xf, sw[2], base[2]);
        float z3 = fmaf(xf, sw[3], base[3]);
        z0 = fmaf(r0, v_[0][0], z0); z0 = fmaf(r1, v_[0][1], z0);
        z0 = fmaf(r2, v_[0][2], z0); z0 = fmaf(r3, v_[0][3], z0);
        z1 = fmaf(r0, v_[1][0], z1); z1 = fmaf(r1, v_[1][1], z1);
        z1 = fmaf(r2, v_[1][2], z1); z1 = fmaf(r3, v_[1][3], z1);
        z2 = fmaf(r0, v_[2][0], z2); z2 = fmaf(r1, v_[2][1], z2);
        z2 = fmaf(r2, v_[2][2], z2); z2 = fmaf(r3, v_[2][3], z2);
        z3 = fmaf(r0, v_[3][0], z3); z3 = fmaf(r1, v_[3][1], z3);
        z3 = fmaf(r2, v_[3][2], z3); z3 = fmaf(r3, v_[3][3], z3);
        r0 = __builtin_amdgcn_rcpf(__builtin_amdgcn_exp2f(z0) + 1.0f);
        r1 = __builtin_amdgcn_rcpf(__builtin_amdgcn_exp2f(z1) + 1.0f);
        r2 = __builtin_amdgcn_rcpf(__builtin_amdgcn_exp2f(z2) + 1.0f);
        r3 = __builtin_amdgcn_rcpf(__builtin_amdgcn_exp2f(z3) + 1.0f);
        float corr = fmaf(lat, (r2 + r3) - 1.0f, 1.0f - r2);
        float nl   = fmaf(lat, (r0 + r1) - 1.0f, 1.0f - r0);
        const size_t off = (size_t)(t_out0 + i) * BB;
        cO[off] = corr;
        lO[off] = nl;
        float lp = yls[i * 64 + lane] ? corr : (1.0f - corr);
        lossAcc += fmaxf(__builtin_amdgcn_logf(lp) * 0.6931471805599453f, -100.0f);
        lat = nl;
    }

    #pragma unroll
    for (int o = 32; o >= 1; o >>= 1) lossAcc += __shfl_xor(lossAcc, o, 64);
    if (lane == 0) lossPart[blockIdx.x] = lossAcc;
}

// Reduce 1024 per-block partials -> final mean NLL
__global__ void reduce_k(const float* __restrict__ part, float* __restrict__ loss) {
    float acc = 0.f;
    for (int i = threadIdx.x; i < 1024; i += 256) acc += part[i];
    #pragma unroll
    for (int o = 32; o >= 1; o >>= 1) acc += __shfl_xor(acc, o, 64);
    __shared__ float w[4];
    if ((threadIdx.x & 63) == 0) w[threadIdx.x >> 6] = acc;
    __syncthreads();
    if (threadIdx.x == 0) {
        float t = w[0] + w[1] + w[2] + w[3];
        *loss = t * (-1.0f / ((float)TT * (float)BB));
    }
}

extern "C" void kernel_launch(void* const* d_in, const int* in_sizes, int n_in,
                              void* d_out, int out_size, void* d_ws, size_t ws_size,
                              hipStream_t stream) {
    const float* x    = (const float*)d_in[0];
    const float* y    = (const float*)d_in[1];
    const float* pr   = (const float*)d_in[2];
    const float* W_ih = (const float*)d_in[3];
    const float* W_hh = (const float*)d_in[4];
    const float* b_ih = (const float*)d_in[5];
    const float* b_hh = (const float*)d_in[6];
    float* out = (float*)d_out;
    float* lossPart = (float*)d_ws;  // 1024 floats

    bkt_rnn_k<<<NCH * 64, 64, 0, stream>>>(x, y, pr, W_ih, W_hh, b_ih, b_hh, out, lossPart);
    reduce_k<<<1, 256, 0, stream>>>(lossPart, out + 2 * (size_t)TT * BB);
}

// Round 7
// 121.495 us; speedup vs baseline: 1.4238x; 1.0723x over previous
//
#include <hip/hip_runtime.h>

#define TT 1024
#define BB 4096
#define CHUNK 64
#define WARM 160
#define NCH (TT / CHUNK)        // 16 chunks
#define NWMAX 7                 // (WARM+CHUNK)/32 words max

// One wave per block; one LANE per element (all 4 hidden units in-lane).
// x consumed as per-lane bitmask words (packed in prologue, parked in LDS,
// 1 ds_read_b32 per 32 steps); y as 2 register words. No per-step LDS/loads.
// State r_j = 1/(exp2(z'_j)+1); h_j = 1-2 r_j; params p_j = 1-r_j.
__launch_bounds__(64, 1)
__global__ void bkt_rnn_k(const float* __restrict__ x,
                          const float* __restrict__ y,
                          const float* __restrict__ prior,
                          const float* __restrict__ W_ih,
                          const float* __restrict__ W_hh,
                          const float* __restrict__ b_ih,
                          const float* __restrict__ b_hh,
                          float* __restrict__ out,
                          float* __restrict__ lossPart)
{
    __shared__ unsigned xls[NWMAX * 64];   // x bit-words, [word][lane]

    const int lane = threadIdx.x;
    const int c  = blockIdx.x >> 6;        // chunk 0..15
    const int eg = blockIdx.x & 63;        // element group
    const int e  = eg * 64 + lane;

    const int t_out0  = c * CHUNK;
    const int nwarm   = (t_out0 > WARM) ? WARM : t_out0;   // multiple of 32
    const int t_start = t_out0 - nwarm;
    const int nww     = nwarm >> 5;        // warm words (0,2,4,5)
    const int nwords  = nww + 2;           // + 2 output words

    // ---- prologue: per-lane bit-pack of x (coalesced dword wave-loads)
    const float* xp = x + (size_t)t_start * BB + e;
    for (int wd = 0; wd < nwords; ++wd) {
        unsigned m = 0;
        #pragma unroll
        for (int i = 0; i < 32; ++i)
            if (xp[(size_t)(wd * 32 + i) * BB] != 0.0f) m |= (1u << i);
        xls[wd * 64 + lane] = m;           // own-lane slot; no barrier needed
    }
    const float* ypb = y + (size_t)t_out0 * BB + e;
    unsigned yw0 = 0, yw1 = 0;
    #pragma unroll
    for (int i = 0; i < 32; ++i) {
        if (ypb[(size_t)i * BB] != 0.0f)        yw0 |= (1u << i);
        if (ypb[(size_t)(i + 32) * BB] != 0.0f) yw1 |= (1u << i);
    }

    // ---- constants (r-form, S = 2*log2(e) folded); scalar values
    const float S = 2.8853900817779268f;
    float base[4], sw[4], v_[4][4];
    #pragma unroll
    for (int jj = 0; jj < 4; ++jj) {
        float rowsum = W_hh[jj * 4 + 0] + W_hh[jj * 4 + 1] + W_hh[jj * 4 + 2] + W_hh[jj * 4 + 3];
        base[jj] = S * (b_ih[jj] + b_hh[jj] + rowsum);
        sw[jj]   = S * W_ih[jj];
        #pragma unroll
        for (int kk = 0; kk < 4; ++kk) v_[jj][kk] = -2.f * S * W_hh[jj * 4 + kk];
    }

    float lat = 1.0f / (1.0f + __builtin_amdgcn_exp2f(-1.4426950408889634f * prior[0]));
    float r0 = 0.5f, r1 = 0.5f, r2 = 0.5f, r3 = 0.5f;   // h = 0
    float lossAcc = 0.0f;

    // one RNN+latent step given x-bit as float; tree-form dot (3 chain hops)
    auto step = [&](float xf) {
        float z0 = fmaf(r0, v_[0][0], fmaf(r1, v_[0][1], fmaf(xf, sw[0], base[0])))
                 + fmaf(r2, v_[0][2], r3 * v_[0][3]);
        float z1 = fmaf(r0, v_[1][0], fmaf(r1, v_[1][1], fmaf(xf, sw[1], base[1])))
                 + fmaf(r2, v_[1][2], r3 * v_[1][3]);
        float z2 = fmaf(r0, v_[2][0], fmaf(r1, v_[2][1], fmaf(xf, sw[2], base[2])))
                 + fmaf(r2, v_[2][2], r3 * v_[2][3]);
        float z3 = fmaf(r0, v_[3][0], fmaf(r1, v_[3][1], fmaf(xf, sw[3], base[3])))
                 + fmaf(r2, v_[3][2], r3 * v_[3][3]);
        r0 = __builtin_amdgcn_rcpf(__builtin_amdgcn_exp2f(z0) + 1.0f);
        r1 = __builtin_amdgcn_rcpf(__builtin_amdgcn_exp2f(z1) + 1.0f);
        r2 = __builtin_amdgcn_rcpf(__builtin_amdgcn_exp2f(z2) + 1.0f);
        r3 = __builtin_amdgcn_rcpf(__builtin_amdgcn_exp2f(z3) + 1.0f);
    };

    // ---- warmup (h + latent, no outputs)
    for (int wd = 0; wd < nww; ++wd) {
        unsigned m = xls[wd * 64 + lane];
        #pragma unroll 8
        for (int i = 0; i < 32; ++i) {
            step((float)((m >> i) & 1u));
            lat = fmaf(lat, (r0 + r1) - 1.0f, 1.0f - r0);
        }
    }

    // ---- output: 2 static words of 32 steps, direct coalesced stores + BCE
    unsigned mo0 = xls[nww * 64 + lane];
    unsigned mo1 = xls[(nww + 1) * 64 + lane];
    float* cO = out + (size_t)t_out0 * BB + e;
    float* lO = cO + (size_t)TT * BB;

    auto outblock = [&](unsigned mw, unsigned yw, int tb) {
        #pragma unroll 8
        for (int i = 0; i < 32; ++i) {
            step((float)((mw >> i) & 1u));
            float corr = fmaf(lat, (r2 + r3) - 1.0f, 1.0f - r2);
            float nl   = fmaf(lat, (r0 + r1) - 1.0f, 1.0f - r0);
            const size_t off = (size_t)(tb + i) * BB;
            cO[off] = corr;
            lO[off] = nl;
            float lp = ((yw >> i) & 1u) ? corr : (1.0f - corr);
            lossAcc += fmaxf(__builtin_amdgcn_logf(lp) * 0.6931471805599453f, -100.0f);
            lat = nl;
        }
    };
    outblock(mo0, yw0, 0);
    outblock(mo1, yw1, 32);

    #pragma unroll
    for (int o = 32; o >= 1; o >>= 1) lossAcc += __shfl_xor(lossAcc, o, 64);
    if (lane == 0) lossPart[blockIdx.x] = lossAcc;
}

// Reduce 1024 per-block partials -> final mean NLL
__global__ void reduce_k(const float* __restrict__ part, float* __restrict__ loss) {
    float acc = 0.f;
    for (int i = threadIdx.x; i < 1024; i += 256) acc += part[i];
    #pragma unroll
    for (int o = 32; o >= 1; o >>= 1) acc += __shfl_xor(acc, o, 64);
    __shared__ float w[4];
    if ((threadIdx.x & 63) == 0) w[threadIdx.x >> 6] = acc;
    __syncthreads();
    if (threadIdx.x == 0) {
        float t = w[0] + w[1] + w[2] + w[3];
        *loss = t * (-1.0f / ((float)TT * (float)BB));
    }
}

extern "C" void kernel_launch(void* const* d_in, const int* in_sizes, int n_in,
                              void* d_out, int out_size, void* d_ws, size_t ws_size,
                              hipStream_t stream) {
    const float* x    = (const float*)d_in[0];
    const float* y    = (const float*)d_in[1];
    const float* pr   = (const float*)d_in[2];
    const float* W_ih = (const float*)d_in[3];
    const float* W_hh = (const float*)d_in[4];
    const float* b_ih = (const float*)d_in[5];
    const float* b_hh = (const float*)d_in[6];
    float* out = (float*)d_out;
    float* lossPart = (float*)d_ws;  // 1024 floats

    bkt_rnn_k<<<NCH * 64, 64, 0, stream>>>(x, y, pr, W_ih, W_hh, b_ih, b_hh, out, lossPart);
    reduce_k<<<1, 256, 0, stream>>>(lossPart, out + 2 * (size_t)TT * BB);
}